// Round 16
// baseline (145.051 us; speedup 1.0000x reference)
//
#include <hip/hip_runtime.h>

// ws layout (needs >= 56 MB):
//   [0x0000000, 0x0400000) k_norm f32 [256][4096]            (4 MB)
//   [0x0400000, 0x0401000) tw float2[512]                    (4 KB)
//   [0x0420000, 0x0440000) Wbf bf16 [256 m][256 h]           (128 KB)
//   [0x0800000, 0x1800000) Kst float2 [256][8192]            (16 MB)
//   [0x1800000, 0x3800000) g bf16 [16][256][4096]            (32 MB)

#define C1f 0.92387953251128674f
#define S1f 0.38268343236508977f
#define C2f 0.70710678118654752f

typedef __attribute__((ext_vector_type(8))) short bf16x8;
typedef __attribute__((ext_vector_type(4))) float f32x4;

static __device__ __forceinline__ unsigned short f2bf(float f) {
  unsigned u = __float_as_uint(f);
  u += 0x7FFFu + ((u >> 16) & 1u);
  return (unsigned short)(u >> 16);
}

static __device__ __forceinline__ void cmul(float& ar, float& ai, float br, float bi) {
  float t = ar * br - ai * bi;
  ai = ar * bi + ai * br;
  ar = t;
}

// tanh-form GeLU; exp2-native constant pre-folds log2(e)
static __device__ __forceinline__ float gelu_t(float x) {
  float x2 = x * x;
  float t = x * __builtin_fmaf(0.044715f, x2, 1.f);
  float e = __builtin_amdgcn_exp2f(-2.3022650966f * t);
  return x * __builtin_amdgcn_rcpf(1.f + e);
}

// intra-wave LDS fence (rule #18): stops compiler reorder across exchanges
#define LGKM()                                              \
  {                                                         \
    asm volatile("s_waitcnt lgkmcnt(0)" ::: "memory");      \
    __builtin_amdgcn_sched_barrier(0);                      \
  }

// w32^k, k=0..15 (S3 twiddles; forward -sin, inverse +sin)
__device__ __constant__ float W32C[16] = {
  1.f, 0.98078528040323044913f, 0.92387953251128675613f, 0.83146961230254523708f,
  0.70710678118654752440f, 0.55557023301960222474f, 0.38268343236508977173f,
  0.19509032201612826785f, 0.f, -0.19509032201612826785f, -0.38268343236508977173f,
  -0.55557023301960222474f, -0.70710678118654752440f, -0.83146961230254523708f,
  -0.92387953251128675613f, -0.98078528040323044913f};
__device__ __constant__ float W32S[16] = {
  0.f, 0.19509032201612826785f, 0.38268343236508977173f, 0.55557023301960222474f,
  0.70710678118654752440f, 0.83146961230254523708f, 0.92387953251128675613f,
  0.98078528040323044913f, 1.f, 0.98078528040323044913f, 0.92387953251128675613f,
  0.83146961230254523708f, 0.70710678118654752440f, 0.55557023301960222474f,
  0.38268343236508977173f, 0.19509032201612826785f};

// forward 16-pt DFT, DIF radix-2, in-place; output slot p holds X[rev4(p)].
// ZH=true: entry slots 8..15 known zero.
template <bool ZH>
static __device__ __forceinline__ void dft16_fwd_t(float* xr, float* xi) {
  const float wr[8] = {1.f, C1f, C2f, S1f, 0.f, -S1f, -C2f, -C1f};
  const float wi[8] = {0.f, -S1f, -C2f, -C1f, -1.f, -C1f, -C2f, -S1f};
#pragma unroll
  for (int j = 0; j < 8; ++j) {
    if (ZH) {
      float ar = xr[j], ai = xi[j];
      xr[j + 8] = ar * wr[j] - ai * wi[j];
      xi[j + 8] = ar * wi[j] + ai * wr[j];
    } else {
      float ar = xr[j], ai = xi[j], br = xr[j + 8], bi = xi[j + 8];
      xr[j] = ar + br; xi[j] = ai + bi;
      float dr = ar - br, di = ai - bi;
      xr[j + 8] = dr * wr[j] - di * wi[j];
      xi[j + 8] = dr * wi[j] + di * wr[j];
    }
  }
#pragma unroll
  for (int h = 0; h < 2; ++h) {
#pragma unroll
    for (int j = 0; j < 4; ++j) {
      int i0 = h * 8 + j, i1 = i0 + 4;
      float ar = xr[i0], ai = xi[i0], br = xr[i1], bi = xi[i1];
      xr[i0] = ar + br; xi[i0] = ai + bi;
      float dr = ar - br, di = ai - bi;
      xr[i1] = dr * wr[2 * j] - di * wi[2 * j];
      xi[i1] = dr * wi[2 * j] + di * wr[2 * j];
    }
  }
#pragma unroll
  for (int h = 0; h < 4; ++h) {
    int base = h * 4;
    {
      int i0 = base, i1 = base + 2;
      float ar = xr[i0], ai = xi[i0], br = xr[i1], bi = xi[i1];
      xr[i0] = ar + br; xi[i0] = ai + bi;
      xr[i1] = ar - br; xi[i1] = ai - bi;
    }
    {
      int i0 = base + 1, i1 = base + 3;
      float ar = xr[i0], ai = xi[i0], br = xr[i1], bi = xi[i1];
      xr[i0] = ar + br; xi[i0] = ai + bi;
      float dr = ar - br, di = ai - bi;
      xr[i1] = di; xi[i1] = -dr;
    }
  }
#pragma unroll
  for (int h = 0; h < 8; ++h) {
    int i0 = h * 2, i1 = i0 + 1;
    float ar = xr[i0], ai = xi[i0], br = xr[i1], bi = xi[i1];
    xr[i0] = ar + br; xi[i0] = ai + bi;
    xr[i1] = ar - br; xi[i1] = ai - bi;
  }
}

// inverse 16-pt DFT (conjugate mirror); HALF=true -> only outputs 0..7
template <bool HALF>
static __device__ __forceinline__ void dft16_inv_t(float* xr, float* xi) {
  const float wr[8] = {1.f, C1f, C2f, S1f, 0.f, -S1f, -C2f, -C1f};
  const float wi[8] = {0.f, S1f, C2f, C1f, 1.f, C1f, C2f, S1f};
#pragma unroll
  for (int h = 0; h < 8; ++h) {
    int i0 = h * 2, i1 = i0 + 1;
    float ar = xr[i0], ai = xi[i0], br = xr[i1], bi = xi[i1];
    xr[i0] = ar + br; xi[i0] = ai + bi;
    xr[i1] = ar - br; xi[i1] = ai - bi;
  }
#pragma unroll
  for (int h = 0; h < 4; ++h) {
    int base = h * 4;
    {
      int i0 = base, i1 = base + 2;
      float ar = xr[i0], ai = xi[i0], tr = xr[i1], ti = xi[i1];
      xr[i0] = ar + tr; xi[i0] = ai + ti;
      xr[i1] = ar - tr; xi[i1] = ai - ti;
    }
    {
      int i0 = base + 1, i1 = base + 3;
      float ar = xr[i0], ai = xi[i0], br = xr[i1], bi = xi[i1];
      float tr = -bi, ti = br;
      xr[i0] = ar + tr; xi[i0] = ai + ti;
      xr[i1] = ar - tr; xi[i1] = ai - ti;
    }
  }
#pragma unroll
  for (int h = 0; h < 2; ++h) {
#pragma unroll
    for (int j = 0; j < 4; ++j) {
      int i0 = h * 8 + j, i1 = i0 + 4;
      float br = xr[i1], bi = xi[i1];
      float tr = br * wr[2 * j] - bi * wi[2 * j];
      float ti = br * wi[2 * j] + bi * wr[2 * j];
      float ar = xr[i0], ai = xi[i0];
      xr[i0] = ar + tr; xi[i0] = ai + ti;
      xr[i1] = ar - tr; xi[i1] = ai - ti;
    }
  }
#pragma unroll
  for (int j = 0; j < 8; ++j) {
    int i0 = j, i1 = j + 8;
    float br = xr[i1], bi = xi[i1];
    float tr = br * wr[j] - bi * wi[j];
    float ti = br * wi[j] + bi * wr[j];
    float ar = xr[i0], ai = xi[i0];
    xr[i0] = ar + tr; xi[i0] = ai + ti;
    if (!HALF) { xr[i1] = ar - tr; xi[i1] = ai - ti; }
  }
}

#define REV_INIT constexpr int REV[16] = {0, 8, 4, 12, 2, 10, 6, 14, 1, 9, 5, 13, 3, 11, 7, 15}

#define TWCHAIN(XR, XI, CR, CI)                         \
  {                                                     \
    float pr_ = (CR), pi_ = (CI);                       \
    cmul(XR[8], XI[8], pr_, pi_);                       \
    _Pragma("unroll") for (int k = 2; k < 16; ++k) {    \
      cmul(pr_, pi_, (CR), (CI));                       \
      cmul(XR[REV[k]], XI[REV[k]], pr_, pi_);           \
    }                                                   \
  }

// single-problem forward (kfft only) — r15-proven
static __device__ __forceinline__ void fft8192_fwd(float* xr, float* xi, float* lbuf,
                                                   int t, const float2* __restrict__ tw) {
  REV_INIT;
  int bs1 = t + (t >> 5);
  int bg1 = ((t >> 5) << 9) + (t & 31) + ((t >> 5) << 4);
  int qq = t & 1;
  int bg2 = 33 * (t >> 1) + qq;
  dft16_fwd_t<true>(xr, xi);
  {
    float2 w1 = tw[t];
    TWCHAIN(xr, xi, w1.x, w1.y);
  }
#pragma unroll
  for (int j = 0; j < 16; ++j) lbuf[bs1 + 528 * REV[j]] = xr[j];
  __syncthreads();
#pragma unroll
  for (int m = 0; m < 16; ++m) xr[m] = lbuf[bg1 + 33 * m];
  __syncthreads();
#pragma unroll
  for (int j = 0; j < 16; ++j) lbuf[bs1 + 528 * REV[j]] = xi[j];
  __syncthreads();
#pragma unroll
  for (int m = 0; m < 16; ++m) xi[m] = lbuf[bg1 + 33 * m];
  dft16_fwd_t<false>(xr, xi);
  {
    float2 w1 = tw[(t & 31) << 4];
    TWCHAIN(xr, xi, w1.x, w1.y);
  }
  LGKM();
#pragma unroll
  for (int j = 0; j < 16; ++j) lbuf[bg1 + 33 * REV[j]] = xr[j];
  LGKM();
#pragma unroll
  for (int m = 0; m < 16; ++m) xr[m] = lbuf[bg2 + 2 * m];
  LGKM();
#pragma unroll
  for (int j = 0; j < 16; ++j) lbuf[bg1 + 33 * REV[j]] = xi[j];
  LGKM();
#pragma unroll
  for (int m = 0; m < 16; ++m) xi[m] = lbuf[bg2 + 2 * m];
  dft16_fwd_t<false>(xr, xi);
  if (qq) {
#pragma unroll
    for (int k = 1; k < 16; ++k) cmul(xr[REV[k]], xi[REV[k]], W32C[k], -W32S[k]);
  }
  float sgn = qq ? -1.f : 1.f;
#pragma unroll
  for (int j = 0; j < 16; ++j) {
    float pr = __shfl_xor(xr[j], 1);
    float pi = __shfl_xor(xi[j], 1);
    xr[j] = sgn * xr[j] + pr;
    xi[j] = sgn * xi[j] + pi;
  }
}

// ---------------- setup: build normalized k, twiddles, Wbf ----------------
__global__ void __launch_bounds__(256) gconv_setup(
    const float* __restrict__ kernels,  // [8][1][256][32]
    const float* __restrict__ W_out,    // [256][256]
    float* __restrict__ k_norm,         // [256][4096]
    float2* __restrict__ tw,            // [512]
    unsigned short* __restrict__ Wbf)   // bf16 [256 m][256 h]
{
  int blk = blockIdx.x;
  int tid = threadIdx.x;
  if (blk < 256) {
    int h = blk;
    __shared__ float red[256];
    float val[16];
    float ss = 0.0f;
#pragma unroll
    for (int r = 0; r < 16; ++r) {
      int l = tid + 256 * r;
      int i;
      if (l < 32) i = 0;
      else if (l < 64) i = 1;
      else i = (31 - __clz(l)) - 4;
      int off = (i == 0) ? 0 : (16 << i);
      int s = (i <= 1) ? 1 : (1 << (i - 1));
      float mult = (float)(1 << (7 - i));
      int j = l - off;
      const float* kb = kernels + ((size_t)i * 256 + h) * 32;
      float v;
      if (s == 1) {
        v = kb[j];
      } else {
        float x = ((float)j + 0.5f) / (float)s - 0.5f;
        x = fminf(fmaxf(x, 0.0f), 31.0f);
        float xf = floorf(x);
        int x0 = (int)xf;
        int x1 = min(x0 + 1, 31);
        float w = x - xf;
        v = kb[x0] * (1.0f - w) + kb[x1] * w;
      }
      v *= mult;
      val[r] = v;
      ss += v * v;
    }
    red[tid] = ss;
    __syncthreads();
    for (int o = 128; o > 0; o >>= 1) {
      if (tid < o) red[tid] += red[tid + o];
      __syncthreads();
    }
    float inv = 1.0f / sqrtf(red[0]);
#pragma unroll
    for (int r = 0; r < 16; ++r)
      k_norm[(size_t)h * 4096 + tid + 256 * r] = val[r] * inv;
  } else if (blk < 258) {
    int idx = (blk - 256) * 256 + tid;  // 0..511
    double ang = -6.283185307179586477 * (double)idx / 8192.0;
    tw[idx] = make_float2((float)cos(ang), (float)sin(ang));
  } else {
    int o = (blk - 258) * 256 + tid;    // Wbf[m][h] = bf16(W_out[m][h])
    Wbf[o] = f2bf(W_out[o]);
  }
}

// ---------------- kernel FFT: K_hat (permuted layout), D and 1/N folded ---
__global__ void __launch_bounds__(512, 4) gconv_kfft(
    const float* __restrict__ k_norm,
    const float* __restrict__ Dvec,
    const float2* __restrict__ tw,
    float2* __restrict__ Kst)           // [256][8192], index h*8192 + t*16 + j
{
  __shared__ float lbuf[8448];
  int h = blockIdx.x;
  int t = threadIdx.x;
  float xr[16], xi[16];
  const float* kn = k_norm + ((size_t)h << 12);
#pragma unroll
  for (int m = 0; m < 8; ++m) { xr[m] = kn[t + (m << 9)]; xi[m] = 0.f; }
#pragma unroll
  for (int m = 8; m < 16; ++m) { xr[m] = 0.f; xi[m] = 0.f; }
  fft8192_fwd(xr, xi, lbuf, t, tw);
  float Dh = Dvec[h];
  const float sc = 1.0f / 8192.0f;
  float2* out = Kst + ((size_t)h << 13) + (t << 4);
#pragma unroll
  for (int j = 0; j < 16; ++j)
    out[j] = make_float2((xr[j] + Dh) * sc, xi[j] * sc);
}

// ---- main: TWO problems per thread (A: pb=pp, B: pb=pp+4), phase-pipelined
// so each problem's VALU blocks fill the other's transport windows. One 33KB
// buffer; A/B transport phases are disjoint; 2 extra barriers protect the
// cross-wave hand-offs (A.I2 reads -> B.T1 writes; A.T4 reads -> B.I3 writes).
__global__ void __launch_bounds__(512, 4) gconv_main(
    const float* __restrict__ u,
    const float2* __restrict__ tw,
    const float2* __restrict__ Kst,
    unsigned short* __restrict__ g)     // bf16 [16][256][4096]
{
  __shared__ float lbuf[8448];
  REV_INIT;
  int blk = blockIdx.x;
  int h = blk & 255;
  int pp = blk >> 8;                    // 0..3 ; A: pp/pp+8, B: pp+4/pp+12
  int t = threadIdx.x;
  int bs1 = t + (t >> 5);
  int bg1 = ((t >> 5) << 9) + (t & 31) + ((t >> 5) << 4);
  int qq = t & 1;
  int bg2 = 33 * (t >> 1) + qq;
  float sgn = qq ? -1.f : 1.f;
  float2 w1t = tw[t];
  float2 w2t = tw[(t & 31) << 4];
  const float2* kr = Kst + ((size_t)h << 13) + (t << 4);

#define T1W(X) {_Pragma("unroll") for (int j = 0; j < 16; ++j) lbuf[bs1 + 528 * REV[j]] = X[j];}
#define T1R(X) {_Pragma("unroll") for (int m = 0; m < 16; ++m) X[m] = lbuf[bg1 + 33 * m];}
#define I2W(X) {_Pragma("unroll") for (int j = 0; j < 16; ++j) lbuf[bg1 + 33 * REV[j]] = X[j];}
#define I2R(X) {_Pragma("unroll") for (int m = 0; m < 16; ++m) X[m] = lbuf[bg2 + 2 * m];}
#define I3W(X) {_Pragma("unroll") for (int m = 0; m < 16; ++m) lbuf[bg2 + 2 * m] = X[m];}
#define I3R(X) {_Pragma("unroll") for (int j = 0; j < 16; ++j) X[j] = lbuf[bg1 + 33 * REV[j]];}
#define T4W(X) {_Pragma("unroll") for (int m = 0; m < 16; ++m) lbuf[bg1 + 33 * m] = X[m];}
#define T4R(X) {_Pragma("unroll") for (int j = 0; j < 16; ++j) X[j] = lbuf[bs1 + 528 * REV[j]];}
#define S4(XR, XI) {_Pragma("unroll") for (int j = 0; j < 16; ++j) { \
    float pr = __shfl_xor(XR[j], 1); float pi = __shfl_xor(XI[j], 1); \
    XR[j] = sgn * XR[j] + pr; XI[j] = sgn * XI[j] + pi; }}
#define S3TWF(XR, XI) if (qq) {_Pragma("unroll") for (int k = 1; k < 16; ++k) \
    cmul(XR[REV[k]], XI[REV[k]], W32C[k], -W32S[k]);}
#define S3TWI(XR, XI) if (qq) {_Pragma("unroll") for (int k = 1; k < 16; ++k) \
    cmul(XR[REV[k]], XI[REV[k]], W32C[k], W32S[k]);}
#define MULTK(XR, XI) {_Pragma("unroll") for (int j = 0; j < 16; ++j) { \
    float2 kv = kr[j]; cmul(XR[j], XI[j], kv.x, kv.y); }}

  float xrA[16], xiA[16], xrB[16], xiB[16];
  const float* uA0 = u + ((size_t)(pp * 256 + h) << 12);
  const float* uA1 = u + ((size_t)((pp + 8) * 256 + h) << 12);
  const float* uB0 = u + ((size_t)((pp + 4) * 256 + h) << 12);
  const float* uB1 = u + ((size_t)((pp + 12) * 256 + h) << 12);
#pragma unroll
  for (int m = 0; m < 8; ++m) { xrA[m] = uA0[t + (m << 9)]; xiA[m] = uA1[t + (m << 9)]; }
  // A.C0
  dft16_fwd_t<true>(xrA, xiA);
  TWCHAIN(xrA, xiA, w1t.x, w1t.y);
  // A.T1 with B.load + B.C0 stuffed
  T1W(xrA);
#pragma unroll
  for (int m = 0; m < 8; ++m) { xrB[m] = uB0[t + (m << 9)]; xiB[m] = uB1[t + (m << 9)]; }
  dft16_fwd_t<true>(xrB, xiB);
  TWCHAIN(xrB, xiB, w1t.x, w1t.y);
  __syncthreads();
  T1R(xrA);
  __syncthreads();
  T1W(xiA);
  __syncthreads();
  T1R(xiA);
  // A.C1
  dft16_fwd_t<false>(xrA, xiA);
  TWCHAIN(xrA, xiA, w2t.x, w2t.y);
  // A.I2 (intra-wave)
  LGKM(); I2W(xrA);
  LGKM(); I2R(xrA);
  LGKM(); I2W(xiA);
  LGKM(); I2R(xiA);
  __syncthreads();                // all waves' A.I2 reads before B.T1 writes
  // B.T1 with A.C2 stuffed
  T1W(xrB);
  dft16_fwd_t<false>(xrA, xiA);
  S3TWF(xrA, xiA);
  S4(xrA, xiA);
  MULTK(xrA, xiA);
  S4(xrA, xiA);
  S3TWI(xrA, xiA);
  dft16_inv_t<false>(xrA, xiA);
  __syncthreads();
  T1R(xrB);
  __syncthreads();
  T1W(xiB);
  __syncthreads();
  T1R(xiB);
  // B.C1
  dft16_fwd_t<false>(xrB, xiB);
  TWCHAIN(xrB, xiB, w2t.x, w2t.y);
  // B.I2 (intra-wave)
  LGKM(); I2W(xrB);
  LGKM(); I2R(xrB);
  LGKM(); I2W(xiB);
  LGKM(); I2R(xiB);
  // A.I3 (own-region; disjoint from other waves' B.I2 own-regions)
  LGKM(); I3W(xrA);
  LGKM(); I3R(xrA);
  LGKM(); I3W(xiA);
  LGKM(); I3R(xiA);
  // A.C3
  TWCHAIN(xrA, xiA, w2t.x, -w2t.y);
  dft16_inv_t<false>(xrA, xiA);
  // B.C2 (stuffs A.T4 lead-in)
  dft16_fwd_t<false>(xrB, xiB);
  S3TWF(xrB, xiB);
  S4(xrB, xiB);
  MULTK(xrB, xiB);
  S4(xrB, xiB);
  S3TWI(xrB, xiB);
  dft16_inv_t<false>(xrB, xiB);
  // A.T4 (cross-wave)
  LGKM(); T4W(xrA);
  __syncthreads();
  T4R(xrA);
  __syncthreads();
  T4W(xiA);
  __syncthreads();
  T4R(xiA);
  // A.C4 + store
  TWCHAIN(xrA, xiA, w1t.x, -w1t.y);
  dft16_inv_t<true>(xrA, xiA);
  {
    unsigned short* g0 = g + ((size_t)(pp * 256 + h) << 12) + t;
    unsigned short* g1 = g + ((size_t)((pp + 8) * 256 + h) << 12) + t;
#pragma unroll
    for (int m = 0; m < 8; ++m) {
      g0[m << 9] = f2bf(gelu_t(xrA[m]));
      g1[m << 9] = f2bf(gelu_t(xiA[m]));
    }
  }
  __syncthreads();                // all waves' A.T4 cross-reads before B.I3
  // B.I3
  LGKM(); I3W(xrB);
  LGKM(); I3R(xrB);
  LGKM(); I3W(xiB);
  LGKM(); I3R(xiB);
  // B.C3
  TWCHAIN(xrB, xiB, w2t.x, -w2t.y);
  dft16_inv_t<false>(xrB, xiB);
  // B.T4
  LGKM(); T4W(xrB);
  __syncthreads();
  T4R(xrB);
  __syncthreads();
  T4W(xiB);
  __syncthreads();
  T4R(xiB);
  // B.C4 + store
  TWCHAIN(xrB, xiB, w1t.x, -w1t.y);
  dft16_inv_t<true>(xrB, xiB);
  {
    unsigned short* g0 = g + ((size_t)((pp + 4) * 256 + h) << 12) + t;
    unsigned short* g1 = g + ((size_t)((pp + 12) * 256 + h) << 12) + t;
#pragma unroll
    for (int m = 0; m < 8; ++m) {
      g0[m << 9] = f2bf(gelu_t(xrB[m]));
      g1[m << 9] = f2bf(gelu_t(xiB[m]));
    }
  }
}

// -------- output projection (MFMA): out[b][m][l] = sum_h W[m][h] g[b][h][l] + b[m]
__global__ void __launch_bounds__(256) gconv_out(
    const unsigned short* __restrict__ g,   // bf16 [16][256][4096]
    const unsigned short* __restrict__ Wbf, // bf16 [256 m][256 h]
    const float* __restrict__ b_out,        // [256]
    float* __restrict__ out)                // [16][256][4096]
{
  __shared__ unsigned short As[128][40];    // [m][k]
  __shared__ unsigned short Bs[32][132];    // [k][l]
  int l0 = blockIdx.x * 128;
  int m0 = blockIdx.y * 128;
  int b  = blockIdx.z;
  int tid = threadIdx.x;
  int lane = tid & 63, wid = tid >> 6;
  int wm = (wid >> 1) * 64, wl = (wid & 1) * 64;
  int lhi = lane >> 4, llo = lane & 15;
  f32x4 acc[4][4];
#pragma unroll
  for (int a = 0; a < 4; ++a)
#pragma unroll
    for (int c = 0; c < 4; ++c) acc[a][c] = (f32x4){0.f, 0.f, 0.f, 0.f};

  for (int ks = 0; ks < 8; ++ks) {
    int k0 = ks * 32;
#pragma unroll
    for (int i = 0; i < 2; ++i) {
      int idx = tid + i * 256;
      int m = idx >> 2, c = idx & 3;
      *(uint4*)&As[m][c * 8] =
          *(const uint4*)(Wbf + ((size_t)(m0 + m) << 8) + k0 + c * 8);
      int k = idx >> 4, cc = idx & 15;
      const unsigned short* gp =
          g + ((size_t)(b * 256 + k0 + k) << 12) + l0 + cc * 8;
      ((uint2*)&Bs[k][cc * 8])[0] = ((const uint2*)gp)[0];
      ((uint2*)&Bs[k][cc * 8])[1] = ((const uint2*)gp)[1];
    }
    __syncthreads();
    int kk = lhi * 8;
    bf16x8 af[4], bfr[4];
#pragma unroll
    for (int f = 0; f < 4; ++f)
      af[f] = *(bf16x8*)&As[wm + f * 16 + llo][kk];
#pragma unroll
    for (int f = 0; f < 4; ++f) {
      bf16x8 v;
#pragma unroll
      for (int j = 0; j < 8; ++j)
        v[j] = (short)Bs[kk + j][wl + f * 16 + llo];
      bfr[f] = v;
    }
#pragma unroll
    for (int fm = 0; fm < 4; ++fm)
#pragma unroll
      for (int fl = 0; fl < 4; ++fl)
        acc[fm][fl] = __builtin_amdgcn_mfma_f32_16x16x32_bf16(
            af[fm], bfr[fl], acc[fm][fl], 0, 0, 0);
    __syncthreads();
  }
#pragma unroll
  for (int fm = 0; fm < 4; ++fm) {
#pragma unroll
    for (int r = 0; r < 4; ++r) {
      int m = m0 + wm + fm * 16 + lhi * 4 + r;
      float bias = b_out[m];
      float* op = out + ((size_t)(b * 256 + m) << 12) + l0 + wl + llo;
#pragma unroll
      for (int fl = 0; fl < 4; ++fl)
        op[fl * 16] = acc[fm][fl][r] + bias;
    }
  }
}

extern "C" void kernel_launch(void* const* d_in, const int* in_sizes, int n_in,
                              void* d_out, int out_size, void* d_ws, size_t ws_size,
                              hipStream_t stream) {
  (void)in_sizes; (void)n_in; (void)out_size; (void)ws_size;
  const float* u       = (const float*)d_in[0];
  const float* kernels = (const float*)d_in[1];
  const float* Dvec    = (const float*)d_in[2];
  const float* W_out   = (const float*)d_in[3];
  const float* b_out   = (const float*)d_in[4];
  float* out = (float*)d_out;
  char* ws = (char*)d_ws;

  float*  k_norm = (float*)(ws);
  float2* tw     = (float2*)(ws + (4u << 20));
  unsigned short* Wbf = (unsigned short*)(ws + (4u << 20) + (128u << 10));
  float2* Kst    = (float2*)(ws + (8u << 20));
  unsigned short* g = (unsigned short*)(ws + (24u << 20));

  gconv_setup<<<514, 256, 0, stream>>>(kernels, W_out, k_norm, tw, Wbf);
  gconv_kfft<<<256, 512, 0, stream>>>(k_norm, Dvec, tw, Kst);
  gconv_main<<<1024, 512, 0, stream>>>(u, tw, Kst, g);
  dim3 gd(32, 2, 16);
  gconv_out<<<gd, 256, 0, stream>>>(g, Wbf, b_out, out);
}

// Round 17
// 106.436 us; speedup vs baseline: 1.3628x; 1.3628x over previous
//
#include <hip/hip_runtime.h>

// ws layout (needs >= 56 MB):
//   [0x0000000, 0x0400000) k_norm f32 [256][4096]            (4 MB)
//   [0x0400000, 0x0401000) tw float2[512]                    (4 KB)
//   [0x0420000, 0x0440000) Wbf bf16 [256 m][256 h]           (128 KB)
//   [0x0800000, 0x1800000) Kst float2 [256][8192]            (16 MB)
//   [0x1800000, 0x3800000) g bf16 [16][256][4096]            (32 MB)

#define C1f 0.92387953251128674f
#define S1f 0.38268343236508977f
#define C2f 0.70710678118654752f

typedef __attribute__((ext_vector_type(8))) short bf16x8;
typedef __attribute__((ext_vector_type(4))) float f32x4;

static __device__ __forceinline__ unsigned short f2bf(float f) {
  unsigned u = __float_as_uint(f);
  u += 0x7FFFu + ((u >> 16) & 1u);
  return (unsigned short)(u >> 16);
}

static __device__ __forceinline__ void cmul(float& ar, float& ai, float br, float bi) {
  float t = ar * br - ai * bi;
  ai = ar * bi + ai * br;
  ar = t;
}

// tanh-form GeLU; exp2-native (v_exp_f32 is exp2): constant pre-folds log2(e)
static __device__ __forceinline__ float gelu_t(float x) {
  float x2 = x * x;
  float t = x * __builtin_fmaf(0.044715f, x2, 1.f);
  float e = __builtin_amdgcn_exp2f(-2.3022650966f * t);   // exp(-1.59577 t)
  return x * __builtin_amdgcn_rcpf(1.f + e);
}

// intra-wave LDS fence: DS pipe is in-order per wave; this only stops the
// compiler from reordering LDS ops across the exchange (rule #18).
#define LGKM()                                              \
  {                                                         \
    asm volatile("s_waitcnt lgkmcnt(0)" ::: "memory");      \
    __builtin_amdgcn_sched_barrier(0);                      \
  }

// w32^k, k=0..15 (S3 twiddles; forward -sin, inverse +sin)
__device__ __constant__ float W32C[16] = {
  1.f, 0.98078528040323044913f, 0.92387953251128675613f, 0.83146961230254523708f,
  0.70710678118654752440f, 0.55557023301960222474f, 0.38268343236508977173f,
  0.19509032201612826785f, 0.f, -0.19509032201612826785f, -0.38268343236508977173f,
  -0.55557023301960222474f, -0.70710678118654752440f, -0.83146961230254523708f,
  -0.92387953251128675613f, -0.98078528040323044913f};
__device__ __constant__ float W32S[16] = {
  0.f, 0.19509032201612826785f, 0.38268343236508977173f, 0.55557023301960222474f,
  0.70710678118654752440f, 0.83146961230254523708f, 0.92387953251128675613f,
  0.98078528040323044913f, 1.f, 0.98078528040323044913f, 0.92387953251128675613f,
  0.83146961230254523708f, 0.70710678118654752440f, 0.55557023301960222474f,
  0.38268343236508977173f, 0.19509032201612826785f};

// forward 16-pt DFT, DIF radix-2, in-place; output slot p holds X[rev4(p)].
// ZH=true: entry slots 8..15 are known zero (zero-padded tail) -> L1 collapses.
template <bool ZH>
static __device__ __forceinline__ void dft16_fwd_t(float* xr, float* xi) {
  const float wr[8] = {1.f, C1f, C2f, S1f, 0.f, -S1f, -C2f, -C1f};
  const float wi[8] = {0.f, -S1f, -C2f, -C1f, -1.f, -C1f, -C2f, -S1f};
#pragma unroll
  for (int j = 0; j < 8; ++j) {
    if (ZH) {
      float ar = xr[j], ai = xi[j];
      xr[j + 8] = ar * wr[j] - ai * wi[j];
      xi[j + 8] = ar * wi[j] + ai * wr[j];
      // xr[j], xi[j] unchanged (a + 0)
    } else {
      float ar = xr[j], ai = xi[j], br = xr[j + 8], bi = xi[j + 8];
      xr[j] = ar + br; xi[j] = ai + bi;
      float dr = ar - br, di = ai - bi;
      xr[j + 8] = dr * wr[j] - di * wi[j];
      xi[j + 8] = dr * wi[j] + di * wr[j];
    }
  }
#pragma unroll
  for (int h = 0; h < 2; ++h) {
#pragma unroll
    for (int j = 0; j < 4; ++j) {
      int i0 = h * 8 + j, i1 = i0 + 4;
      float ar = xr[i0], ai = xi[i0], br = xr[i1], bi = xi[i1];
      xr[i0] = ar + br; xi[i0] = ai + bi;
      float dr = ar - br, di = ai - bi;
      xr[i1] = dr * wr[2 * j] - di * wi[2 * j];
      xi[i1] = dr * wi[2 * j] + di * wr[2 * j];
    }
  }
#pragma unroll
  for (int h = 0; h < 4; ++h) {
    int base = h * 4;
    {
      int i0 = base, i1 = base + 2;
      float ar = xr[i0], ai = xi[i0], br = xr[i1], bi = xi[i1];
      xr[i0] = ar + br; xi[i0] = ai + bi;
      xr[i1] = ar - br; xi[i1] = ai - bi;
    }
    {
      int i0 = base + 1, i1 = base + 3;
      float ar = xr[i0], ai = xi[i0], br = xr[i1], bi = xi[i1];
      xr[i0] = ar + br; xi[i0] = ai + bi;
      float dr = ar - br, di = ai - bi;
      xr[i1] = di; xi[i1] = -dr;
    }
  }
#pragma unroll
  for (int h = 0; h < 8; ++h) {
    int i0 = h * 2, i1 = i0 + 1;
    float ar = xr[i0], ai = xi[i0], br = xr[i1], bi = xi[i1];
    xr[i0] = ar + br; xi[i0] = ai + bi;
    xr[i1] = ar - br; xi[i1] = ai - bi;
  }
}

// inverse 16-pt DFT (conjugate mirror, no scaling); input slot p = X[rev4(p)].
// HALF=true computes only natural-order outputs 0..7.
template <bool HALF>
static __device__ __forceinline__ void dft16_inv_t(float* xr, float* xi) {
  const float wr[8] = {1.f, C1f, C2f, S1f, 0.f, -S1f, -C2f, -C1f};
  const float wi[8] = {0.f, S1f, C2f, C1f, 1.f, C1f, C2f, S1f};
#pragma unroll
  for (int h = 0; h < 8; ++h) {
    int i0 = h * 2, i1 = i0 + 1;
    float ar = xr[i0], ai = xi[i0], br = xr[i1], bi = xi[i1];
    xr[i0] = ar + br; xi[i0] = ai + bi;
    xr[i1] = ar - br; xi[i1] = ai - bi;
  }
#pragma unroll
  for (int h = 0; h < 4; ++h) {
    int base = h * 4;
    {
      int i0 = base, i1 = base + 2;
      float ar = xr[i0], ai = xi[i0], tr = xr[i1], ti = xi[i1];
      xr[i0] = ar + tr; xi[i0] = ai + ti;
      xr[i1] = ar - tr; xi[i1] = ai - ti;
    }
    {
      int i0 = base + 1, i1 = base + 3;
      float ar = xr[i0], ai = xi[i0], br = xr[i1], bi = xi[i1];
      float tr = -bi, ti = br;
      xr[i0] = ar + tr; xi[i0] = ai + ti;
      xr[i1] = ar - tr; xi[i1] = ai - ti;
    }
  }
#pragma unroll
  for (int h = 0; h < 2; ++h) {
#pragma unroll
    for (int j = 0; j < 4; ++j) {
      int i0 = h * 8 + j, i1 = i0 + 4;
      float br = xr[i1], bi = xi[i1];
      float tr = br * wr[2 * j] - bi * wi[2 * j];
      float ti = br * wi[2 * j] + bi * wr[2 * j];
      float ar = xr[i0], ai = xi[i0];
      xr[i0] = ar + tr; xi[i0] = ai + ti;
      xr[i1] = ar - tr; xi[i1] = ai - ti;
    }
  }
#pragma unroll
  for (int j = 0; j < 8; ++j) {
    int i0 = j, i1 = j + 8;
    float br = xr[i1], bi = xi[i1];
    float tr = br * wr[j] - bi * wi[j];
    float ti = br * wi[j] + bi * wr[j];
    float ar = xr[i0], ai = xi[i0];
    xr[i0] = ar + tr; xi[i0] = ai + ti;
    if (!HALF) { xr[i1] = ar - tr; xi[i1] = ai - ti; }
  }
}

#define REV_INIT constexpr int REV[16] = {0, 8, 4, 12, 2, 10, 6, 14, 1, 9, 5, 13, 3, 11, 7, 15}

// apply slot-j twiddle w^(REV[j]) by power chain from base (cr,ci)
#define TWCHAIN(XR, XI, CR, CI)                         \
  {                                                     \
    float pr_ = (CR), pi_ = (CI);                       \
    cmul(XR[8], XI[8], pr_, pi_);                       \
    _Pragma("unroll") for (int k = 2; k < 16; ++k) {    \
      cmul(pr_, pi_, (CR), (CI));                       \
      cmul(XR[REV[k]], XI[REV[k]], pr_, pi_);           \
    }                                                   \
  }

// r9 padded addressing (proven): pad p+(p>>5) folded into per-thread bases +
// compile-time const offsets. B2/B3 intra-wave -> LGKM() only (r12-proven).
static __device__ __forceinline__ void fft8192_fwd(float* xr, float* xi, float* lbuf,
                                                   int t, const float2* __restrict__ tw) {
  REV_INIT;
  int bs1 = t + (t >> 5);
  int bg1 = ((t >> 5) << 9) + (t & 31) + ((t >> 5) << 4);
  int qq = t & 1;
  int bg2 = 33 * (t >> 1) + qq;
  dft16_fwd_t<true>(xr, xi);          // entry slots 8..15 are zero
  {
    float2 w1 = tw[t];
    TWCHAIN(xr, xi, w1.x, w1.y);
  }
  // B1 (cross-wave): 3 barriers
#pragma unroll
  for (int j = 0; j < 16; ++j) lbuf[bs1 + 528 * REV[j]] = xr[j];
  __syncthreads();
#pragma unroll
  for (int m = 0; m < 16; ++m) xr[m] = lbuf[bg1 + 33 * m];
  __syncthreads();
#pragma unroll
  for (int j = 0; j < 16; ++j) lbuf[bs1 + 528 * REV[j]] = xi[j];
  __syncthreads();
#pragma unroll
  for (int m = 0; m < 16; ++m) xi[m] = lbuf[bg1 + 33 * m];
  dft16_fwd_t<false>(xr, xi);
  {
    float2 w1 = tw[(t & 31) << 4];
    TWCHAIN(xr, xi, w1.x, w1.y);
  }
  // B2 (intra-wave): no barriers
  LGKM();
#pragma unroll
  for (int j = 0; j < 16; ++j) lbuf[bg1 + 33 * REV[j]] = xr[j];
  LGKM();
#pragma unroll
  for (int m = 0; m < 16; ++m) xr[m] = lbuf[bg2 + 2 * m];
  LGKM();
#pragma unroll
  for (int j = 0; j < 16; ++j) lbuf[bg1 + 33 * REV[j]] = xi[j];
  LGKM();
#pragma unroll
  for (int m = 0; m < 16; ++m) xi[m] = lbuf[bg2 + 2 * m];
  dft16_fwd_t<false>(xr, xi);
  if (qq) {
#pragma unroll
    for (int k = 1; k < 16; ++k) cmul(xr[REV[k]], xi[REV[k]], W32C[k], -W32S[k]);
  }
  float sgn = qq ? -1.f : 1.f;
#pragma unroll
  for (int j = 0; j < 16; ++j) {
    float pr = __shfl_xor(xr[j], 1);
    float pi = __shfl_xor(xi[j], 1);
    xr[j] = sgn * xr[j] + pr;
    xi[j] = sgn * xi[j] + pi;
  }
}

// exact inverse (conjugate twiddles, mirrored); scale 8192 folded into Kst.
static __device__ __forceinline__ void fft8192_inv(float* xr, float* xi, float* lbuf,
                                                   int t, const float2* __restrict__ tw) {
  REV_INIT;
  int bs1 = t + (t >> 5);
  int bg1 = ((t >> 5) << 9) + (t & 31) + ((t >> 5) << 4);
  int qq = t & 1;
  int bg2 = 33 * (t >> 1) + qq;
  float sgn = qq ? -1.f : 1.f;
#pragma unroll
  for (int j = 0; j < 16; ++j) {
    float pr = __shfl_xor(xr[j], 1);
    float pi = __shfl_xor(xi[j], 1);
    xr[j] = sgn * xr[j] + pr;
    xi[j] = sgn * xi[j] + pi;
  }
  if (qq) {
#pragma unroll
    for (int k = 1; k < 16; ++k) cmul(xr[REV[k]], xi[REV[k]], W32C[k], W32S[k]);
  }
  dft16_inv_t<false>(xr, xi);
  // B3 (intra-wave mirror of B2): no barriers
  LGKM();
#pragma unroll
  for (int m = 0; m < 16; ++m) lbuf[bg2 + 2 * m] = xr[m];
  LGKM();
#pragma unroll
  for (int j = 0; j < 16; ++j) xr[j] = lbuf[bg1 + 33 * REV[j]];
  LGKM();
#pragma unroll
  for (int m = 0; m < 16; ++m) lbuf[bg2 + 2 * m] = xi[m];
  LGKM();
#pragma unroll
  for (int j = 0; j < 16; ++j) xi[j] = lbuf[bg1 + 33 * REV[j]];
  {
    float2 w1 = tw[(t & 31) << 4];
    TWCHAIN(xr, xi, w1.x, -w1.y);
  }
  dft16_inv_t<false>(xr, xi);
  // B4 (cross-wave mirror of B1): 3 barriers
  LGKM();
#pragma unroll
  for (int m = 0; m < 16; ++m) lbuf[bg1 + 33 * m] = xr[m];
  __syncthreads();
#pragma unroll
  for (int j = 0; j < 16; ++j) xr[j] = lbuf[bs1 + 528 * REV[j]];
  __syncthreads();
#pragma unroll
  for (int m = 0; m < 16; ++m) lbuf[bg1 + 33 * m] = xi[m];
  __syncthreads();
#pragma unroll
  for (int j = 0; j < 16; ++j) xi[j] = lbuf[bs1 + 528 * REV[j]];
  {
    float2 w1 = tw[t];
    TWCHAIN(xr, xi, w1.x, -w1.y);
  }
  dft16_inv_t<true>(xr, xi);
}

// ---------------- setup: build normalized k, twiddles, Wbf ----------------
__global__ void __launch_bounds__(256) gconv_setup(
    const float* __restrict__ kernels,  // [8][1][256][32]
    const float* __restrict__ W_out,    // [256][256]
    float* __restrict__ k_norm,         // [256][4096]
    float2* __restrict__ tw,            // [512]
    unsigned short* __restrict__ Wbf)   // bf16 [256 m][256 h]
{
  int blk = blockIdx.x;
  int tid = threadIdx.x;
  if (blk < 256) {
    int h = blk;
    __shared__ float red[256];
    float val[16];
    float ss = 0.0f;
#pragma unroll
    for (int r = 0; r < 16; ++r) {
      int l = tid + 256 * r;
      int i;
      if (l < 32) i = 0;
      else if (l < 64) i = 1;
      else i = (31 - __clz(l)) - 4;
      int off = (i == 0) ? 0 : (16 << i);
      int s = (i <= 1) ? 1 : (1 << (i - 1));
      float mult = (float)(1 << (7 - i));
      int j = l - off;
      const float* kb = kernels + ((size_t)i * 256 + h) * 32;
      float v;
      if (s == 1) {
        v = kb[j];
      } else {
        float x = ((float)j + 0.5f) / (float)s - 0.5f;
        x = fminf(fmaxf(x, 0.0f), 31.0f);
        float xf = floorf(x);
        int x0 = (int)xf;
        int x1 = min(x0 + 1, 31);
        float w = x - xf;
        v = kb[x0] * (1.0f - w) + kb[x1] * w;
      }
      v *= mult;
      val[r] = v;
      ss += v * v;
    }
    red[tid] = ss;
    __syncthreads();
    for (int o = 128; o > 0; o >>= 1) {
      if (tid < o) red[tid] += red[tid + o];
      __syncthreads();
    }
    float inv = 1.0f / sqrtf(red[0]);
#pragma unroll
    for (int r = 0; r < 16; ++r)
      k_norm[(size_t)h * 4096 + tid + 256 * r] = val[r] * inv;
  } else if (blk < 258) {
    int idx = (blk - 256) * 256 + tid;  // 0..511
    double ang = -6.283185307179586477 * (double)idx / 8192.0;
    tw[idx] = make_float2((float)cos(ang), (float)sin(ang));
  } else {
    int o = (blk - 258) * 256 + tid;    // Wbf[m][h] = bf16(W_out[m][h])
    Wbf[o] = f2bf(W_out[o]);
  }
}

// ---------------- kernel FFT: K_hat (permuted layout), D and 1/N folded ---
__global__ void __launch_bounds__(512, 4) gconv_kfft(
    const float* __restrict__ k_norm,
    const float* __restrict__ Dvec,
    const float2* __restrict__ tw,
    float2* __restrict__ Kst)           // [256][8192], index h*8192 + t*16 + j
{
  __shared__ float lbuf[8448];
  int h = blockIdx.x;
  int t = threadIdx.x;
  float xr[16], xi[16];
  const float* kn = k_norm + ((size_t)h << 12);
#pragma unroll
  for (int m = 0; m < 8; ++m) { xr[m] = kn[t + (m << 9)]; xi[m] = 0.f; }
#pragma unroll
  for (int m = 8; m < 16; ++m) { xr[m] = 0.f; xi[m] = 0.f; }
  fft8192_fwd(xr, xi, lbuf, t, tw);
  float Dh = Dvec[h];
  const float sc = 1.0f / 8192.0f;
  float2* out = Kst + ((size_t)h << 13) + (t << 4);
#pragma unroll
  for (int j = 0; j < 16; ++j)
    out[j] = make_float2((xr[j] + Dh) * sc, xi[j] * sc);
}

// ---------------- main: fwd FFT (b-pair packed), multiply, inv FFT, gelu --
__global__ void __launch_bounds__(512, 4) gconv_main(
    const float* __restrict__ u,
    const float2* __restrict__ tw,
    const float2* __restrict__ Kst,
    unsigned short* __restrict__ g)     // bf16 [16][256][4096]
{
  __shared__ float lbuf[8448];
  int blk = blockIdx.x;
  int h = blk & 255;
  int pb = blk >> 8;                    // 0..7 ; batches pb and pb+8
  int t = threadIdx.x;
  const float* u0 = u + ((size_t)(pb * 256 + h) << 12);
  const float* u1 = u + ((size_t)((pb + 8) * 256 + h) << 12);
  float xr[16], xi[16];
#pragma unroll
  for (int m = 0; m < 8; ++m) { xr[m] = u0[t + (m << 9)]; xi[m] = u1[t + (m << 9)]; }
#pragma unroll
  for (int m = 8; m < 16; ++m) { xr[m] = 0.f; xi[m] = 0.f; }
  fft8192_fwd(xr, xi, lbuf, t, tw);
  const float2* kr = Kst + ((size_t)h << 13) + (t << 4);
#pragma unroll
  for (int j = 0; j < 16; ++j) {
    float2 kv = kr[j];
    cmul(xr[j], xi[j], kv.x, kv.y);
  }
  fft8192_inv(xr, xi, lbuf, t, tw);
  unsigned short* g0 = g + ((size_t)(pb * 256 + h) << 12) + t;
  unsigned short* g1 = g + ((size_t)((pb + 8) * 256 + h) << 12) + t;
#pragma unroll
  for (int m = 0; m < 8; ++m) {
    g0[m << 9] = f2bf(gelu_t(xr[m]));
    g1[m << 9] = f2bf(gelu_t(xi[m]));
  }
}

// -------- output projection (MFMA): out[b][m][l] = sum_h W[m][h] g[b][h][l] + b[m]
__global__ void __launch_bounds__(256) gconv_out(
    const unsigned short* __restrict__ g,   // bf16 [16][256][4096]
    const unsigned short* __restrict__ Wbf, // bf16 [256 m][256 h]
    const float* __restrict__ b_out,        // [256]
    float* __restrict__ out)                // [16][256][4096]
{
  __shared__ unsigned short As[128][40];    // [m][k]
  __shared__ unsigned short Bs[32][132];    // [k][l]
  int l0 = blockIdx.x * 128;
  int m0 = blockIdx.y * 128;
  int b  = blockIdx.z;
  int tid = threadIdx.x;
  int lane = tid & 63, wid = tid >> 6;
  int wm = (wid >> 1) * 64, wl = (wid & 1) * 64;
  int lhi = lane >> 4, llo = lane & 15;
  f32x4 acc[4][4];
#pragma unroll
  for (int a = 0; a < 4; ++a)
#pragma unroll
    for (int c = 0; c < 4; ++c) acc[a][c] = (f32x4){0.f, 0.f, 0.f, 0.f};

  for (int ks = 0; ks < 8; ++ks) {
    int k0 = ks * 32;
#pragma unroll
    for (int i = 0; i < 2; ++i) {
      int idx = tid + i * 256;
      int m = idx >> 2, c = idx & 3;
      *(uint4*)&As[m][c * 8] =
          *(const uint4*)(Wbf + ((size_t)(m0 + m) << 8) + k0 + c * 8);
      int k = idx >> 4, cc = idx & 15;
      const unsigned short* gp =
          g + ((size_t)(b * 256 + k0 + k) << 12) + l0 + cc * 8;
      ((uint2*)&Bs[k][cc * 8])[0] = ((const uint2*)gp)[0];
      ((uint2*)&Bs[k][cc * 8])[1] = ((const uint2*)gp)[1];
    }
    __syncthreads();
    int kk = lhi * 8;
    bf16x8 af[4], bfr[4];
#pragma unroll
    for (int f = 0; f < 4; ++f)
      af[f] = *(bf16x8*)&As[wm + f * 16 + llo][kk];
#pragma unroll
    for (int f = 0; f < 4; ++f) {
      bf16x8 v;
#pragma unroll
      for (int j = 0; j < 8; ++j)
        v[j] = (short)Bs[kk + j][wl + f * 16 + llo];
      bfr[f] = v;
    }
#pragma unroll
    for (int fm = 0; fm < 4; ++fm)
#pragma unroll
      for (int fl = 0; fl < 4; ++fl)
        acc[fm][fl] = __builtin_amdgcn_mfma_f32_16x16x32_bf16(
            af[fm], bfr[fl], acc[fm][fl], 0, 0, 0);
    __syncthreads();
  }
#pragma unroll
  for (int fm = 0; fm < 4; ++fm) {
#pragma unroll
    for (int r = 0; r < 4; ++r) {
      int m = m0 + wm + fm * 16 + lhi * 4 + r;
      float bias = b_out[m];
      float* op = out + ((size_t)(b * 256 + m) << 12) + l0 + wl + llo;
#pragma unroll
      for (int fl = 0; fl < 4; ++fl)
        op[fl * 16] = acc[fm][fl][r] + bias;
    }
  }
}

extern "C" void kernel_launch(void* const* d_in, const int* in_sizes, int n_in,
                              void* d_out, int out_size, void* d_ws, size_t ws_size,
                              hipStream_t stream) {
  (void)in_sizes; (void)n_in; (void)out_size; (void)ws_size;
  const float* u       = (const float*)d_in[0];
  const float* kernels = (const float*)d_in[1];
  const float* Dvec    = (const float*)d_in[2];
  const float* W_out   = (const float*)d_in[3];
  const float* b_out   = (const float*)d_in[4];
  float* out = (float*)d_out;
  char* ws = (char*)d_ws;

  float*  k_norm = (float*)(ws);
  float2* tw     = (float2*)(ws + (4u << 20));
  unsigned short* Wbf = (unsigned short*)(ws + (4u << 20) + (128u << 10));
  float2* Kst    = (float2*)(ws + (8u << 20));
  unsigned short* g = (unsigned short*)(ws + (24u << 20));

  gconv_setup<<<514, 256, 0, stream>>>(kernels, W_out, k_norm, tw, Wbf);
  gconv_kfft<<<256, 512, 0, stream>>>(k_norm, Dvec, tw, Kst);
  gconv_main<<<2048, 512, 0, stream>>>(u, tw, Kst, g);
  dim3 gd(32, 2, 16);
  gconv_out<<<gd, 256, 0, stream>>>(g, Wbf, b_out, out);
}